// Round 7
// baseline (204.449 us; speedup 1.0000x reference)
//
#include <hip/hip_runtime.h>
#include <stdint.h>
#include <math.h>

// HashingDiscretizer — R12: fp32-exact 3-level 4-ary search, lane-masked
// gathers, pure TLP. No LDS, no bf16 repair, no scratch.
//
// Model (fits R5-R11): a divergent gather costs ~1 cy per ACTIVE lane at
// TA/L1; wave-serialized dependent repair chains are poison (R11: P(any
// lane ambiguous in wave64)=40% x ~1800cy killed the 2-lookup design).
// This version: fp32 exact everywhere (no repair), and the 2nd/3rd level
// loads sit under `if (cal)` so only ~32/64 lanes issue them.
//   ftab[16384] x 16B: {b15,b31,b47, tag=0x5AFE0000|r}
//       one load (all lanes): calibration test + high-key sentinel +
//       dense row r + quadrant pivots  -> c = #{<v} in [0,3]
//   stab[8192][4] x 16B: {b[16c+3], b[16c+7], b[16c+11], 0} -> c1 in [0,3]
//   level 3: bins row direct: j0 = min(4*(4c+c1), 59);
//       bin = j0 + #{bins[r][j0..j0+3] < v}
//       exact: all b_j (j<j0) < v by pivot sortedness; j0=59 clamp OK
//       because c=3,c1=3 => b59 < v, so bin = 59 + cnt still counts b59.
// Poison 0xAA: tag 0xAAAAAAAA fails (tag&0xFFFFE000)==0x5AFE0000 ->
// unwritten rows read as uncalibrated; no clear pass. ws = 768KB.
// Rare (uk>=16384 or calibrated-high-key): generic fallback; absent in
// bench data (fids = arange(8192) -> no high rows written).

#define GOLDEN   0x9E3779B9u
#define OUT_MASK ((1u << 22) - 1u)
#define NBIN  63
#define NPIV  8192
#define NKEY  16384
#define TAGPAT 0x5AFE0000u

typedef float fx4  __attribute__((ext_vector_type(4)));
typedef float fx4u __attribute__((ext_vector_type(4), aligned(4)));
typedef int   ix4  __attribute__((ext_vector_type(4)));
typedef unsigned ux4 __attribute__((ext_vector_type(4)));

// ---------------- build (no atomics, no clear): 1 thread / feature row ----
__global__ __launch_bounds__(256) void build_tables_kernel(
    const int* __restrict__ fids, const float* __restrict__ bins,
    ux4* __restrict__ ftab, fx4* __restrict__ stab, int F)
{
    const int r = blockIdx.x * blockDim.x + threadIdx.x;
    if (r >= F) return;
    const unsigned uk = (unsigned)fids[r];
    const float* src = bins + (size_t)r * NBIN;
    const unsigned tag = TAGPAT | (unsigned)r;       // r < 8192 (13 bits)

    if (uk < (unsigned)NPIV) {
        ux4 q;
        q.x = __float_as_uint(src[15]);
        q.y = __float_as_uint(src[31]);
        q.z = __float_as_uint(src[47]);
        q.w = tag;
        ftab[uk] = q;
        #pragma unroll
        for (int c = 0; c < 4; ++c) {
            fx4 s;
            s.x = src[16 * c + 3];
            s.y = src[16 * c + 7];
            s.z = src[16 * c + 11];
            s.w = 0.0f;
            stab[(uk << 2) + c] = s;
        }
    } else if (uk < (unsigned)NKEY) {
        ux4 q; q.x = 0u; q.y = 0u; q.z = 0u; q.w = tag;
        ftab[uk] = q;    // calibrated high key -> rare path in main
    }
}

// ---------------- generic fallback ----------------
__device__ __forceinline__ void hd_fallback(
    int k, float v, const int* __restrict__ fids, const float* __restrict__ bins,
    int F, int fsteps, float& okey, float& oval)
{
    int lo = 0, hi = F;
    for (int s = 0; s < fsteps; ++s) {
        int  mid  = (lo + hi) >> 1;
        int  mids = min(mid, F - 1);
        int  fv   = fids[mids];
        bool valid = lo < hi;
        bool right = valid && (fv < k);
        lo = right ? mid + 1 : lo;
        hi = (valid && !right) ? mid : hi;
    }
    const int  idx_safe   = min(lo, F - 1);
    const bool calibrated = (fids[idx_safe] == k);
    const float* brow = bins + (size_t)idx_safe * NBIN;
    int blo = 0, bhi = NBIN;
    #pragma unroll
    for (int s = 0; s < 6; ++s) {
        int   mid  = (blo + bhi) >> 1;
        int   mids = min(mid, NBIN - 1);
        float bv   = brow[mids];
        bool  valid = blo < bhi;
        bool  right = valid && (bv < v);
        blo = right ? mid + 1 : blo;
        bhi = (valid && !right) ? mid : bhi;
    }
    const uint32_t h = ((uint32_t)k * GOLDEN + (uint32_t)blo) * GOLDEN;
    okey = calibrated ? (float)(h & OUT_MASK) : (float)((uint32_t)k & OUT_MASK);
    oval = calibrated ? 1.0f : v;
}

// ---------------- main: 1 element / thread, no LDS ----------------
__global__ __launch_bounds__(256) void hd_main_kernel(
    const int* __restrict__ keys, const float* __restrict__ vals,
    const int* __restrict__ fids, const float* __restrict__ bins,
    const ux4* __restrict__ ftab, const fx4* __restrict__ stab,
    float* __restrict__ out_keys, float* __restrict__ out_vals,
    int n, int F, int fsteps)
{
    const int i = blockIdx.x * (int)blockDim.x + (int)threadIdx.x;
    if (i >= n) return;

    const int   k = __builtin_nontemporal_load(keys + i);
    const float v = __builtin_nontemporal_load(vals + i);
    const unsigned uk = (unsigned)k;

    // ---- L1: one 16B gather for every lane ----
    const ux4 fr = ftab[uk < (unsigned)NKEY ? uk : 0u];
    const unsigned tag     = fr.w;
    const bool     written = (tag & 0xFFFFE000u) == TAGPAT;
    const bool     low     = uk < (unsigned)NPIV;
    const bool     cal     = written && low;
    const bool     rare    = (uk >= (unsigned)NKEY) || (written && !low);

    float ok = (float)(uk & OUT_MASK);
    float ov = v;

    // ---- L2 + L3: only calibrated lanes issue these gathers ----
    if (cal) {
        const unsigned r = tag & 0x1FFFu;
        const int c  = (__uint_as_float(fr.x) < v)
                     + (__uint_as_float(fr.y) < v)
                     + (__uint_as_float(fr.z) < v);
        const fx4 sr = stab[(uk << 2) + (unsigned)c];
        const int c1 = (sr.x < v) + (sr.y < v) + (sr.z < v);
        const int j0 = min(4 * (4 * c + c1), 59);
        const fx4u qr = *reinterpret_cast<const fx4u*>(
            bins + (size_t)r * NBIN + j0);
        const int bin = j0 + (qr.x < v) + (qr.y < v) + (qr.z < v) + (qr.w < v);
        const uint32_t h = (uk * GOLDEN + (uint32_t)bin) * GOLDEN;
        ok = (float)(h & OUT_MASK);
        ov = 1.0f;
    }

    // ---- cold generic path (absent in bench data) ----
    if (__builtin_expect(rare, 0))
        hd_fallback(k, v, fids, bins, F, fsteps, ok, ov);

    __builtin_nontemporal_store(ok, out_keys + i);
    __builtin_nontemporal_store(ov, out_vals + i);
}

// Pure binary-search kernel: used only if the workspace is insufficient.
__global__ __launch_bounds__(256) void hd_simple_kernel(
    const int* __restrict__ keys, const float* __restrict__ vals,
    const int* __restrict__ fids, const float* __restrict__ bins,
    float* __restrict__ out_keys, float* __restrict__ out_vals,
    int n, int F, int fsteps)
{
    const int gid = blockIdx.x * blockDim.x + threadIdx.x;
    const int i0 = gid * 4;
    if (i0 >= n) return;
    #pragma unroll
    for (int j = 0; j < 4; ++j) {
        int idx = min(i0 + j, n - 1);
        float okey, oval;
        hd_fallback(keys[idx], vals[idx], fids, bins, F, fsteps, okey, oval);
        if (i0 + j < n) { out_keys[i0 + j] = okey; out_vals[i0 + j] = oval; }
    }
}

extern "C" void kernel_launch(void* const* d_in, const int* in_sizes, int n_in,
                              void* d_out, int out_size, void* d_ws, size_t ws_size,
                              hipStream_t stream) {
    const int*   keys = (const int*)d_in[0];
    const float* vals = (const float*)d_in[1];
    const int*   fids = (const int*)d_in[2];
    const float* bins = (const float*)d_in[3];

    const int n = in_sizes[0];
    const int F = in_sizes[2];

    int fsteps = 0;
    while ((1 << fsteps) < F + 1) ++fsteps;

    float* out_keys = (float*)d_out;
    float* out_vals = (float*)d_out + n;

    // ws: ftab (256 KB) | stab (512 KB)
    const size_t ftab_bytes = (size_t)NKEY * 16;
    const size_t stab_bytes = (size_t)NPIV * 4 * 16;
    const size_t ws_need    = ftab_bytes + stab_bytes;   // 768 KB

    const bool fast = (ws_size >= ws_need) && (in_sizes[3] == F * NBIN) &&
                      (F <= NPIV);

    if (fast) {
        ux4* ftab = (ux4*)d_ws;
        fx4* stab = (fx4*)((char*)d_ws + ftab_bytes);

        build_tables_kernel<<<(F + 255) / 256, 256, 0, stream>>>(
            fids, bins, ftab, stab, F);

        const int threads = 256;
        const int nblocks = (n + threads - 1) / threads;
        hd_main_kernel<<<nblocks, threads, 0, stream>>>(
            keys, vals, fids, bins, ftab, stab,
            out_keys, out_vals, n, F, fsteps);
    } else {
        const int threads = 256;
        const int grid = (n + threads * 4 - 1) / (threads * 4);
        hd_simple_kernel<<<grid, threads, 0, stream>>>(
            keys, vals, fids, bins, out_keys, out_vals, n, F, fsteps);
    }
}

// Round 8
// 159.842 us; speedup vs baseline: 1.2791x; 1.2791x over previous
//
#include <hip/hip_runtime.h>
#include <stdint.h>
#include <math.h>

// HashingDiscretizer — R13: R5/R9 champion structure (LDS header + one-line
// qtab gather) with DOUBLE the TLP: 8B LDS headers -> 72KB LDS/block ->
// 2 x 1024-thr blocks per CU -> 32 waves/CU (R5 was capped at 16).
//
// Six-round summary: LDS-header structure is empirically best (62us);
// all no-LDS variants regressed (global tables miss L1; short-lived
// 1-elem/thread blocks churn). R5's untested headroom = occupancy.
//
// LDS header spiv8[8192] x 8B: {bf16ceil(b15), bf16ceil(b31),
//   bf16ceil(b47), tag16=0x6000|uk}. Ceil => Bf < v IMPLIES b < v, so
//   q_bf <= q_true. Exact repair: after the fp32 64B quadrant gather,
//   cnt==16 means pivot_q < v -> bump q and re-gather (P~1%, q<3 bound).
//   All bin arithmetic is fp32-exact; no bf16 ambiguity anywhere else.
// scal[8192] bytes in LDS: sentinel for keys 8192..16383 (rare path).
// qtab[8192][64] f32 global (2MB): row=256B, quadrant q = one 64B line.
// Poison 0xAA: tag16=0xAAAA fails (tag==0x6000|uk); scal 0xAA not in
// [0x40,0x7F]; no clear pass needed. Named scalars only (no runtime-
// indexed arrays -> no scratch, lesson of R6-R8).

#define GOLDEN   0x9E3779B9u
#define OUT_MASK ((1u << 22) - 1u)
#define NBIN  63
#define NPIV  8192
#define NKEY  16384

typedef float fx4 __attribute__((ext_vector_type(4)));
typedef int   ix4 __attribute__((ext_vector_type(4)));
typedef unsigned ux2 __attribute__((ext_vector_type(2)));

// bf16 ceil (round toward +inf), -0 canonicalized to +0.
__device__ __forceinline__ unsigned bf16c(float x) {
    const unsigned b = __float_as_uint(x);
    unsigned t = ((int)b >= 0) ? ((b + 0xFFFFu) >> 16) : (b >> 16);
    return (t == 0x8000u) ? 0u : t;
}

// ---------------- build (no atomics, no clear) ----------------
__global__ __launch_bounds__(256) void build_tables_kernel(
    const int* __restrict__ fids, const float* __restrict__ bins,
    float* __restrict__ qtab, ux2* __restrict__ spiv8_g,
    unsigned char* __restrict__ scal_g, int F)
{
    const int t = blockIdx.x * blockDim.x + threadIdx.x;
    if (t >= F * 64) return;
    const int r = t >> 6;
    const int j = t & 63;
    const unsigned uk = (unsigned)fids[r];
    const float* src = bins + (size_t)r * NBIN;

    if (uk < (unsigned)NPIV) {
        qtab[((size_t)uk << 6) + j] = (j < NBIN) ? src[j] : INFINITY;
        if (j == 0) {
            const unsigned B15 = bf16c(src[15]);
            const unsigned B31 = bf16c(src[31]);
            const unsigned B47 = bf16c(src[47]);
            const unsigned tag = 0x6000u | uk;        // uk < 8192
            ux2 p;
            p.x = B15 | (B31 << 16);
            p.y = B47 | (tag << 16);
            spiv8_g[uk] = p;
        }
    } else if (uk < (unsigned)NKEY && j == 0) {
        scal_g[uk - NPIV] = (unsigned char)(0x40u | (uk & 63u));
    }
}

// ---------------- generic fallback ----------------
__device__ __forceinline__ void hd_fallback(
    int k, float v, const int* __restrict__ fids, const float* __restrict__ bins,
    int F, int fsteps, float& okey, float& oval)
{
    int lo = 0, hi = F;
    for (int s = 0; s < fsteps; ++s) {
        int  mid  = (lo + hi) >> 1;
        int  mids = min(mid, F - 1);
        int  fv   = fids[mids];
        bool valid = lo < hi;
        bool right = valid && (fv < k);
        lo = right ? mid + 1 : lo;
        hi = (valid && !right) ? mid : hi;
    }
    const int  idx_safe   = min(lo, F - 1);
    const bool calibrated = (fids[idx_safe] == k);
    const float* brow = bins + (size_t)idx_safe * NBIN;
    int blo = 0, bhi = NBIN;
    #pragma unroll
    for (int s = 0; s < 6; ++s) {
        int   mid  = (blo + bhi) >> 1;
        int   mids = min(mid, NBIN - 1);
        float bv   = brow[mids];
        bool  valid = blo < bhi;
        bool  right = valid && (bv < v);
        blo = right ? mid + 1 : blo;
        bhi = (valid && !right) ? mid : bhi;
    }
    const uint32_t h = ((uint32_t)k * GOLDEN + (uint32_t)blo) * GOLDEN;
    okey = calibrated ? (float)(h & OUT_MASK) : (float)((uint32_t)k & OUT_MASK);
    oval = calibrated ? 1.0f : v;
}

__device__ __forceinline__ int hd_cmp8(fx4 a, fx4 b, float v) {
    return (a.x < v) + (a.y < v) + (a.z < v) + (a.w < v)
         + (b.x < v) + (b.y < v) + (b.z < v) + (b.w < v);
}

// fp32-exact bin within/after quadrant q (bf16 header may underestimate q:
// bump while all 16 quadrant values < v; terminates at true quadrant).
__device__ __forceinline__ int hd_quad_bin(const char* qb, unsigned u,
                                           float v, int q)
{
    for (;;) {
        const char* p = qb + ((u << 8) + (unsigned)(q << 6));
        const fx4 a = *reinterpret_cast<const fx4*>(p);
        const fx4 b = *reinterpret_cast<const fx4*>(p + 16);
        const fx4 c = *reinterpret_cast<const fx4*>(p + 32);
        const fx4 d = *reinterpret_cast<const fx4*>(p + 48);
        const int cnt = hd_cmp8(a, b, v) + hd_cmp8(c, d, v);
        if (__builtin_expect(cnt == 16 && q < 3, 0)) { ++q; continue; }
        return (q << 4) + cnt;
    }
}

// ---------------- main ----------------
// 72KB LDS/block -> 2 blocks/CU; min 8 waves/EU pins VGPR <= 64 so the
// 2-block residency (32 waves/CU) cannot be lost to register growth.
__global__ __launch_bounds__(1024, 8) void hd_main_kernel(
    const int* __restrict__ keys, const float* __restrict__ vals,
    const int* __restrict__ fids, const float* __restrict__ bins,
    const float* __restrict__ qtab, const ux2* __restrict__ spiv8_g,
    const unsigned char* __restrict__ scal_g,
    float* __restrict__ out_keys, float* __restrict__ out_vals,
    int n, int F, int fsteps, int nchunks)
{
    extern __shared__ char smem[];
    ux2*      spiv8 = reinterpret_cast<ux2*>(smem);              // 8192 x 8B
    unsigned* scal  = reinterpret_cast<unsigned*>(smem + (size_t)NPIV * 8);

    const int tid = threadIdx.x;
    for (int i = tid; i < NPIV; i += (int)blockDim.x) spiv8[i] = spiv8_g[i];
    const unsigned* scal_g32 = reinterpret_cast<const unsigned*>(scal_g);
    for (int i = tid; i < NPIV / 4; i += (int)blockDim.x) scal[i] = scal_g32[i];
    __syncthreads();

    const unsigned char* scal_b = reinterpret_cast<const unsigned char*>(scal);
    const char* qb = reinterpret_cast<const char*>(qtab);
    const int nthreads = (int)(gridDim.x * blockDim.x);

    for (int c = blockIdx.x * blockDim.x + tid; c < nchunks; c += nthreads) {
        const int i0 = c * 4;
        int   k0, k1, k2, k3;
        float v0, v1, v2, v3;
        const bool full = (i0 + 3 < n);
        if (full) {
            const ix4 ka = __builtin_nontemporal_load(reinterpret_cast<const ix4*>(keys + i0));
            const fx4 va = __builtin_nontemporal_load(reinterpret_cast<const fx4*>(vals + i0));
            k0 = ka.x; k1 = ka.y; k2 = ka.z; k3 = ka.w;
            v0 = va.x; v1 = va.y; v2 = va.z; v3 = va.w;
        } else {
            k0 = keys[min(i0 + 0, n - 1)]; v0 = vals[min(i0 + 0, n - 1)];
            k1 = keys[min(i0 + 1, n - 1)]; v1 = vals[min(i0 + 1, n - 1)];
            k2 = keys[min(i0 + 2, n - 1)]; v2 = vals[min(i0 + 2, n - 1)];
            k3 = keys[min(i0 + 3, n - 1)]; v3 = vals[min(i0 + 3, n - 1)];
        }

        const unsigned u0 = (unsigned)k0, u1 = (unsigned)k1,
                       u2 = (unsigned)k2, u3 = (unsigned)k3;

        // ---- P1: 4 LDS headers (ds_read_b64), back-to-back ----
        const ux2 h0 = spiv8[u0 < (unsigned)NPIV ? u0 : 0u];
        const ux2 h1 = spiv8[u1 < (unsigned)NPIV ? u1 : 0u];
        const ux2 h2 = spiv8[u2 < (unsigned)NPIV ? u2 : 0u];
        const ux2 h3 = spiv8[u3 < (unsigned)NPIV ? u3 : 0u];

        // ---- P2: classify + bf16 quadrant (sound underestimate) ----
#define HD_BF(B) __uint_as_float((B) << 16)
#define HD_P2(J)                                                              \
        const bool cal##J = (u##J < (unsigned)NPIV) &&                        \
                            ((h##J.y >> 16) == (0x6000u | u##J));             \
        const int q##J = (HD_BF(h##J.x & 0xFFFFu) < v##J)                     \
                       + (HD_BF(h##J.x >> 16)     < v##J)                     \
                       + (HD_BF(h##J.y & 0xFFFFu) < v##J);                    \
        const unsigned hs##J = u##J - (unsigned)NPIV;                         \
        const bool rare##J =                                                  \
            (u##J >= (unsigned)NKEY) ||                                       \
            ((hs##J < (unsigned)NPIV) &&                                      \
             (scal_b[hs##J < (unsigned)NPIV ? hs##J : 0u] ==                  \
              (unsigned char)(0x40u | (u##J & 63u))));
        HD_P2(0) HD_P2(1) HD_P2(2) HD_P2(3)
#undef HD_P2
#undef HD_BF

        // ---- P3: per-element fp32 quadrant gather + hash (cal lanes) ----
        float ok0, ok1, ok2, ok3, ov0, ov1, ov2, ov3;
#define HD_P3(J)                                                              \
        if (cal##J) {                                                         \
            const int bin = hd_quad_bin(qb, u##J, v##J, q##J);                \
            const uint32_t h = (u##J * GOLDEN + (uint32_t)bin) * GOLDEN;      \
            ok##J = (float)(h & OUT_MASK);                                    \
            ov##J = 1.0f;                                                     \
        } else {                                                              \
            ok##J = (float)(u##J & OUT_MASK);                                 \
            ov##J = v##J;                                                     \
        }
        HD_P3(0) HD_P3(1) HD_P3(2) HD_P3(3)
#undef HD_P3

        // ---- cold path (absent in bench data) ----
        if (__builtin_expect(rare0 | rare1 | rare2 | rare3, 0)) {
            if (rare0) hd_fallback(k0, v0, fids, bins, F, fsteps, ok0, ov0);
            if (rare1) hd_fallback(k1, v1, fids, bins, F, fsteps, ok1, ov1);
            if (rare2) hd_fallback(k2, v2, fids, bins, F, fsteps, ok2, ov2);
            if (rare3) hd_fallback(k3, v3, fids, bins, F, fsteps, ok3, ov3);
        }

        if (full) {
            fx4 s;
            s.x = ok0; s.y = ok1; s.z = ok2; s.w = ok3;
            __builtin_nontemporal_store(s, reinterpret_cast<fx4*>(out_keys + i0));
            s.x = ov0; s.y = ov1; s.z = ov2; s.w = ov3;
            __builtin_nontemporal_store(s, reinterpret_cast<fx4*>(out_vals + i0));
        } else {
            if (i0 + 0 < n) { out_keys[i0 + 0] = ok0; out_vals[i0 + 0] = ov0; }
            if (i0 + 1 < n) { out_keys[i0 + 1] = ok1; out_vals[i0 + 1] = ov1; }
            if (i0 + 2 < n) { out_keys[i0 + 2] = ok2; out_vals[i0 + 2] = ov2; }
            if (i0 + 3 < n) { out_keys[i0 + 3] = ok3; out_vals[i0 + 3] = ov3; }
        }
    }
}

// Pure binary-search kernel: used only if LDS or workspace is insufficient.
__global__ __launch_bounds__(256) void hd_simple_kernel(
    const int* __restrict__ keys, const float* __restrict__ vals,
    const int* __restrict__ fids, const float* __restrict__ bins,
    float* __restrict__ out_keys, float* __restrict__ out_vals,
    int n, int F, int fsteps)
{
    const int gid = blockIdx.x * blockDim.x + threadIdx.x;
    const int i0 = gid * 4;
    if (i0 >= n) return;
    #pragma unroll
    for (int j = 0; j < 4; ++j) {
        int idx = min(i0 + j, n - 1);
        float okey, oval;
        hd_fallback(keys[idx], vals[idx], fids, bins, F, fsteps, okey, oval);
        if (i0 + j < n) { out_keys[i0 + j] = okey; out_vals[i0 + j] = oval; }
    }
}

extern "C" void kernel_launch(void* const* d_in, const int* in_sizes, int n_in,
                              void* d_out, int out_size, void* d_ws, size_t ws_size,
                              hipStream_t stream) {
    const int*   keys = (const int*)d_in[0];
    const float* vals = (const float*)d_in[1];
    const int*   fids = (const int*)d_in[2];
    const float* bins = (const float*)d_in[3];

    const int n = in_sizes[0];
    const int F = in_sizes[2];

    int fsteps = 0;
    while ((1 << fsteps) < F + 1) ++fsteps;

    float* out_keys = (float*)d_out;
    float* out_vals = (float*)d_out + n;

    // ws: qtab (2 MB) | spiv8 (64 KB) | scal (8 KB)
    const size_t qtab_bytes = (size_t)NPIV * 64 * sizeof(float);
    const size_t spiv_bytes = (size_t)NPIV * 8;
    const size_t scal_bytes = (size_t)NPIV;
    const size_t ws_need    = qtab_bytes + spiv_bytes + scal_bytes;
    const size_t lds_bytes  = spiv_bytes + scal_bytes;   // 73728 B

    int max_lds = 0;
    hipDeviceGetAttribute(&max_lds, hipDeviceAttributeMaxSharedMemoryPerBlock, 0);

    const bool fast = (ws_size >= ws_need) && ((size_t)max_lds >= lds_bytes) &&
                      (in_sizes[3] == F * NBIN) && (F <= NPIV);

    if (fast) {
        float*         qtab    = (float*)d_ws;
        ux2*           spiv8_g = (ux2*)((char*)d_ws + qtab_bytes);
        unsigned char* scal_g  = (unsigned char*)d_ws + qtab_bytes + spiv_bytes;

        build_tables_kernel<<<(F * 64 + 255) / 256, 256, 0, stream>>>(
            fids, bins, qtab, spiv8_g, scal_g, F);

        (void)hipFuncSetAttribute(
            reinterpret_cast<const void*>(hd_main_kernel),
            hipFuncAttributeMaxDynamicSharedMemorySize, (int)lds_bytes);

        const int threads = 1024;
        const int nblocks = 512;           // 2 blocks/CU -> 32 waves/CU
        const int nchunks = (n + 3) / 4;
        hd_main_kernel<<<nblocks, threads, lds_bytes, stream>>>(
            keys, vals, fids, bins, qtab, spiv8_g, scal_g,
            out_keys, out_vals, n, F, fsteps, nchunks);
    } else {
        const int threads = 256;
        const int grid = (n + threads * 4 - 1) / (threads * 4);
        hd_simple_kernel<<<grid, threads, 0, stream>>>(
            keys, vals, fids, bins, out_keys, out_vals, n, F, fsteps);
    }
}

// Round 9
// 152.899 us; speedup vs baseline: 1.3371x; 1.0454x over previous
//
#include <hip/hip_runtime.h>
#include <stdint.h>
#include <math.h>

// HashingDiscretizer — R14: 8-ary bf16 header -> 32B leaf (2 gathers/elem).
//
// R13 null result: occupancy 36->58% left time unchanged (62 vs 61.5us)
// => NOT latency/TLP-bound. Constant across R5/R9/R13: scattered vector-
// memory instructions into TA/L1 (~2cy per active lane). R5/R13 pay 4
// divergent 16B gathers per calibrated element = ~4 cy/elem ~ measured
// 4.5. Fix: double header fan-out (7 bf16-ceil pivots in the same 16B
// LDS header) -> leaf = ONE 32B half-line (2 gathers) of the SAME qtab.
//   t = #{bf16ceil-pivots < v} in [0,7]  (sound underestimate of true t)
//   bin = 8t + #{qtab_row[8t..8t+7] < v}
//     slot 8t+7 is pivot_t (>= v, adds 0) or +inf pad at t=7 -> exact.
//   bump: all 8 < v && t<7  => true t larger -> t++, re-read (P~3%).
// LDS: spiv16[8192]x16B (pivots+tag) + scal 8KB = 139KB, 1 block/CU
// (R13 proved occupancy above 16 waves/CU buys nothing).
// Poison 0xAA: tag16 0xAAAA != 0x6000|uk (<=0x7FFF); scal 0xAA not in
// [0x40,0x7F] -> unwritten rows read uncalibrated; no clear pass.
// Named scalars only (R6-R8 lesson: runtime-indexed arrays -> scratch).

#define GOLDEN   0x9E3779B9u
#define OUT_MASK ((1u << 22) - 1u)
#define NBIN  63
#define NPIV  8192
#define NKEY  16384

typedef float fx4 __attribute__((ext_vector_type(4)));
typedef int   ix4 __attribute__((ext_vector_type(4)));
typedef unsigned ux4 __attribute__((ext_vector_type(4)));

// bf16 ceil (round toward +inf), -0 canonicalized to +0.
__device__ __forceinline__ unsigned bf16c(float x) {
    const unsigned b = __float_as_uint(x);
    unsigned t = ((int)b >= 0) ? ((b + 0xFFFFu) >> 16) : (b >> 16);
    return (t == 0x8000u) ? 0u : t;
}

// ---------------- build (no atomics, no clear) ----------------
__global__ __launch_bounds__(256) void build_tables_kernel(
    const int* __restrict__ fids, const float* __restrict__ bins,
    float* __restrict__ qtab, ux4* __restrict__ spiv16_g,
    unsigned char* __restrict__ scal_g, int F)
{
    const int t = blockIdx.x * blockDim.x + threadIdx.x;
    if (t >= F * 64) return;
    const int r = t >> 6;
    const int j = t & 63;
    const unsigned uk = (unsigned)fids[r];
    const float* src = bins + (size_t)r * NBIN;

    if (uk < (unsigned)NPIV) {
        qtab[((size_t)uk << 6) + j] = (j < NBIN) ? src[j] : INFINITY;
        if (j == 0) {
            const unsigned p0 = bf16c(src[7]),  p1 = bf16c(src[15]),
                           p2 = bf16c(src[23]), p3 = bf16c(src[31]),
                           p4 = bf16c(src[39]), p5 = bf16c(src[47]),
                           p6 = bf16c(src[55]);
            const unsigned tag = 0x6000u | uk;        // uk < 8192
            ux4 q;
            q.x = p0 | (p1 << 16);
            q.y = p2 | (p3 << 16);
            q.z = p4 | (p5 << 16);
            q.w = p6 | (tag << 16);
            spiv16_g[uk] = q;
        }
    } else if (uk < (unsigned)NKEY && j == 0) {
        scal_g[uk - NPIV] = (unsigned char)(0x40u | (uk & 63u));
    }
}

// ---------------- generic fallback ----------------
__device__ __forceinline__ void hd_fallback(
    int k, float v, const int* __restrict__ fids, const float* __restrict__ bins,
    int F, int fsteps, float& okey, float& oval)
{
    int lo = 0, hi = F;
    for (int s = 0; s < fsteps; ++s) {
        int  mid  = (lo + hi) >> 1;
        int  mids = min(mid, F - 1);
        int  fv   = fids[mids];
        bool valid = lo < hi;
        bool right = valid && (fv < k);
        lo = right ? mid + 1 : lo;
        hi = (valid && !right) ? mid : hi;
    }
    const int  idx_safe   = min(lo, F - 1);
    const bool calibrated = (fids[idx_safe] == k);
    const float* brow = bins + (size_t)idx_safe * NBIN;
    int blo = 0, bhi = NBIN;
    #pragma unroll
    for (int s = 0; s < 6; ++s) {
        int   mid  = (blo + bhi) >> 1;
        int   mids = min(mid, NBIN - 1);
        float bv   = brow[mids];
        bool  valid = blo < bhi;
        bool  right = valid && (bv < v);
        blo = right ? mid + 1 : blo;
        bhi = (valid && !right) ? mid : bhi;
    }
    const uint32_t h = ((uint32_t)k * GOLDEN + (uint32_t)blo) * GOLDEN;
    okey = calibrated ? (float)(h & OUT_MASK) : (float)((uint32_t)k & OUT_MASK);
    oval = calibrated ? 1.0f : v;
}

__device__ __forceinline__ int hd_cmp8(fx4 a, fx4 b, float v) {
    return (a.x < v) + (a.y < v) + (a.z < v) + (a.w < v)
         + (b.x < v) + (b.y < v) + (b.z < v) + (b.w < v);
}

// fp32-exact bin from the 32B leaf window t of the qtab row (bf16 header
// may underestimate t: all-8-less means true window is higher -> bump).
__device__ __forceinline__ int hd_leaf_bin(const char* qb, unsigned u,
                                           float v, int t)
{
    for (;;) {
        const char* p = qb + ((u << 8) + (unsigned)(t << 5));
        const fx4 a = *reinterpret_cast<const fx4*>(p);
        const fx4 b = *reinterpret_cast<const fx4*>(p + 16);
        const int cnt = hd_cmp8(a, b, v);
        if (__builtin_expect(cnt == 8 && t < 7, 0)) { ++t; continue; }
        return (t << 3) + cnt;
    }
}

// ---------------- main ----------------
__global__ __launch_bounds__(1024, 4) void hd_main_kernel(
    const int* __restrict__ keys, const float* __restrict__ vals,
    const int* __restrict__ fids, const float* __restrict__ bins,
    const float* __restrict__ qtab, const ux4* __restrict__ spiv16_g,
    const unsigned char* __restrict__ scal_g,
    float* __restrict__ out_keys, float* __restrict__ out_vals,
    int n, int F, int fsteps, int nchunks)
{
    extern __shared__ char smem[];
    ux4*      spiv16 = reinterpret_cast<ux4*>(smem);             // 8192 x 16B
    unsigned* scal   = reinterpret_cast<unsigned*>(smem + (size_t)NPIV * 16);

    const int tid = threadIdx.x;
    for (int i = tid; i < NPIV; i += (int)blockDim.x) spiv16[i] = spiv16_g[i];
    const unsigned* scal_g32 = reinterpret_cast<const unsigned*>(scal_g);
    for (int i = tid; i < NPIV / 4; i += (int)blockDim.x) scal[i] = scal_g32[i];
    __syncthreads();

    const unsigned char* scal_b = reinterpret_cast<const unsigned char*>(scal);
    const char* qb = reinterpret_cast<const char*>(qtab);
    const int nthreads = (int)(gridDim.x * blockDim.x);

    for (int c = blockIdx.x * blockDim.x + tid; c < nchunks; c += nthreads) {
        const int i0 = c * 4;
        int   k0, k1, k2, k3;
        float v0, v1, v2, v3;
        const bool full = (i0 + 3 < n);
        if (full) {
            const ix4 ka = __builtin_nontemporal_load(reinterpret_cast<const ix4*>(keys + i0));
            const fx4 va = __builtin_nontemporal_load(reinterpret_cast<const fx4*>(vals + i0));
            k0 = ka.x; k1 = ka.y; k2 = ka.z; k3 = ka.w;
            v0 = va.x; v1 = va.y; v2 = va.z; v3 = va.w;
        } else {
            k0 = keys[min(i0 + 0, n - 1)]; v0 = vals[min(i0 + 0, n - 1)];
            k1 = keys[min(i0 + 1, n - 1)]; v1 = vals[min(i0 + 1, n - 1)];
            k2 = keys[min(i0 + 2, n - 1)]; v2 = vals[min(i0 + 2, n - 1)];
            k3 = keys[min(i0 + 3, n - 1)]; v3 = vals[min(i0 + 3, n - 1)];
        }

        const unsigned u0 = (unsigned)k0, u1 = (unsigned)k1,
                       u2 = (unsigned)k2, u3 = (unsigned)k3;

        // ---- P1: 4 LDS headers (ds_read_b128), back-to-back ----
        const ux4 h0 = spiv16[u0 < (unsigned)NPIV ? u0 : 0u];
        const ux4 h1 = spiv16[u1 < (unsigned)NPIV ? u1 : 0u];
        const ux4 h2 = spiv16[u2 < (unsigned)NPIV ? u2 : 0u];
        const ux4 h3 = spiv16[u3 < (unsigned)NPIV ? u3 : 0u];

        // ---- P2: classify + 8-ary bf16 window (sound underestimate) ----
#define HD_BF(B) __uint_as_float((B) << 16)
#define HD_P2(J)                                                              \
        const bool cal##J = (u##J < (unsigned)NPIV) &&                        \
                            ((h##J.w >> 16) == (0x6000u | u##J));             \
        const int t##J = (HD_BF(h##J.x & 0xFFFFu) < v##J)                     \
                       + (HD_BF(h##J.x >> 16)     < v##J)                     \
                       + (HD_BF(h##J.y & 0xFFFFu) < v##J)                     \
                       + (HD_BF(h##J.y >> 16)     < v##J)                     \
                       + (HD_BF(h##J.z & 0xFFFFu) < v##J)                     \
                       + (HD_BF(h##J.z >> 16)     < v##J)                     \
                       + (HD_BF(h##J.w & 0xFFFFu) < v##J);                    \
        const unsigned hs##J = u##J - (unsigned)NPIV;                         \
        const bool rare##J =                                                  \
            (u##J >= (unsigned)NKEY) ||                                       \
            ((hs##J < (unsigned)NPIV) &&                                      \
             (scal_b[hs##J < (unsigned)NPIV ? hs##J : 0u] ==                  \
              (unsigned char)(0x40u | (u##J & 63u))));
        HD_P2(0) HD_P2(1) HD_P2(2) HD_P2(3)
#undef HD_P2
#undef HD_BF

        // ---- P3: 32B leaf gather + hash (calibrated lanes only) ----
        float ok0, ok1, ok2, ok3, ov0, ov1, ov2, ov3;
#define HD_P3(J)                                                              \
        if (cal##J) {                                                         \
            const int bin = hd_leaf_bin(qb, u##J, v##J, t##J);                \
            const uint32_t h = (u##J * GOLDEN + (uint32_t)bin) * GOLDEN;      \
            ok##J = (float)(h & OUT_MASK);                                    \
            ov##J = 1.0f;                                                     \
        } else {                                                              \
            ok##J = (float)(u##J & OUT_MASK);                                 \
            ov##J = v##J;                                                     \
        }
        HD_P3(0) HD_P3(1) HD_P3(2) HD_P3(3)
#undef HD_P3

        // ---- cold path (absent in bench data) ----
        if (__builtin_expect(rare0 | rare1 | rare2 | rare3, 0)) {
            if (rare0) hd_fallback(k0, v0, fids, bins, F, fsteps, ok0, ov0);
            if (rare1) hd_fallback(k1, v1, fids, bins, F, fsteps, ok1, ov1);
            if (rare2) hd_fallback(k2, v2, fids, bins, F, fsteps, ok2, ov2);
            if (rare3) hd_fallback(k3, v3, fids, bins, F, fsteps, ok3, ov3);
        }

        if (full) {
            fx4 s;
            s.x = ok0; s.y = ok1; s.z = ok2; s.w = ok3;
            __builtin_nontemporal_store(s, reinterpret_cast<fx4*>(out_keys + i0));
            s.x = ov0; s.y = ov1; s.z = ov2; s.w = ov3;
            __builtin_nontemporal_store(s, reinterpret_cast<fx4*>(out_vals + i0));
        } else {
            if (i0 + 0 < n) { out_keys[i0 + 0] = ok0; out_vals[i0 + 0] = ov0; }
            if (i0 + 1 < n) { out_keys[i0 + 1] = ok1; out_vals[i0 + 1] = ov1; }
            if (i0 + 2 < n) { out_keys[i0 + 2] = ok2; out_vals[i0 + 2] = ov2; }
            if (i0 + 3 < n) { out_keys[i0 + 3] = ok3; out_vals[i0 + 3] = ov3; }
        }
    }
}

// Pure binary-search kernel: used only if LDS or workspace is insufficient.
__global__ __launch_bounds__(256) void hd_simple_kernel(
    const int* __restrict__ keys, const float* __restrict__ vals,
    const int* __restrict__ fids, const float* __restrict__ bins,
    float* __restrict__ out_keys, float* __restrict__ out_vals,
    int n, int F, int fsteps)
{
    const int gid = blockIdx.x * blockDim.x + threadIdx.x;
    const int i0 = gid * 4;
    if (i0 >= n) return;
    #pragma unroll
    for (int j = 0; j < 4; ++j) {
        int idx = min(i0 + j, n - 1);
        float okey, oval;
        hd_fallback(keys[idx], vals[idx], fids, bins, F, fsteps, okey, oval);
        if (i0 + j < n) { out_keys[i0 + j] = okey; out_vals[i0 + j] = oval; }
    }
}

extern "C" void kernel_launch(void* const* d_in, const int* in_sizes, int n_in,
                              void* d_out, int out_size, void* d_ws, size_t ws_size,
                              hipStream_t stream) {
    const int*   keys = (const int*)d_in[0];
    const float* vals = (const float*)d_in[1];
    const int*   fids = (const int*)d_in[2];
    const float* bins = (const float*)d_in[3];

    const int n = in_sizes[0];
    const int F = in_sizes[2];

    int fsteps = 0;
    while ((1 << fsteps) < F + 1) ++fsteps;

    float* out_keys = (float*)d_out;
    float* out_vals = (float*)d_out + n;

    // ws: qtab (2 MB) | spiv16 (128 KB) | scal (8 KB)
    const size_t qtab_bytes = (size_t)NPIV * 64 * sizeof(float);
    const size_t spiv_bytes = (size_t)NPIV * 16;
    const size_t scal_bytes = (size_t)NPIV;
    const size_t ws_need    = qtab_bytes + spiv_bytes + scal_bytes;
    const size_t lds_bytes  = spiv_bytes + scal_bytes;   // 139264 B

    int max_lds = 0;
    hipDeviceGetAttribute(&max_lds, hipDeviceAttributeMaxSharedMemoryPerBlock, 0);

    const bool fast = (ws_size >= ws_need) && ((size_t)max_lds >= lds_bytes) &&
                      (in_sizes[3] == F * NBIN) && (F <= NPIV);

    if (fast) {
        float*         qtab     = (float*)d_ws;
        ux4*           spiv16_g = (ux4*)((char*)d_ws + qtab_bytes);
        unsigned char* scal_g   = (unsigned char*)d_ws + qtab_bytes + spiv_bytes;

        build_tables_kernel<<<(F * 64 + 255) / 256, 256, 0, stream>>>(
            fids, bins, qtab, spiv16_g, scal_g, F);

        (void)hipFuncSetAttribute(
            reinterpret_cast<const void*>(hd_main_kernel),
            hipFuncAttributeMaxDynamicSharedMemorySize, (int)lds_bytes);

        const int threads = 1024;
        const int nblocks = 256;           // 1 block/CU; LDS fill once per CU
        const int nchunks = (n + 3) / 4;
        hd_main_kernel<<<nblocks, threads, lds_bytes, stream>>>(
            keys, vals, fids, bins, qtab, spiv16_g, scal_g,
            out_keys, out_vals, n, F, fsteps, nchunks);
    } else {
        const int threads = 256;
        const int grid = (n + threads * 4 - 1) / (threads * 4);
        hd_simple_kernel<<<grid, threads, 0, stream>>>(
            keys, vals, fids, bins, out_keys, out_vals, n, F, fsteps);
    }
}

// Round 10
// 146.097 us; speedup vs baseline: 1.3994x; 1.0466x over previous
//
#include <hip/hip_runtime.h>
#include <stdint.h>
#include <math.h>

// HashingDiscretizer — R15: R14 with ONE change — input loads are plain
// cached loads (nontemporal hint removed). NT stores kept (outputs are
// never re-read; write-no-allocate is right for them).
//
// Rationale: R14's counters leave ~60% of the wall as shared stall that
// no resource counter explains (VALU 22%, TA ~9%, LDS ~3%, BW far under
// ceilings, waves proven unhelpful by R13). The one untested constant
// across ALL rounds: __builtin_nontemporal_load on the key/val streams.
// If those take the ~900cy HBM path instead of ~200cy L2-warm, the chain
// HEAD of every iteration eats 4-5x the assumed latency and all waves
// stall together — matching the observations. Single-change round for
// clean attribution.
//
// Structure (R14): 8-ary bf16-ceil header in LDS -> one 32B fp32 leaf.
//   spiv16[8192]x16B LDS: 7 bf16ceil pivots (b7..b55) + tag16=0x6000|uk
//   t = #{bf16ceil pivots < v} (sound underestimate; bump re-read if all
//   8 leaf values < v, P~1%, bounded by t<7)
//   bin = 8t + #{qtab_row[8t..8t+7] < v}; slot 8t+7 = next pivot or +inf.
// scal[8192] LDS bytes: high-key sentinel (rare path, absent in bench).
// qtab[8192][64] f32 global (2MB), row 256B, +inf pad.
// Poison 0xAA reads as uncalibrated everywhere; no clear pass.
// Named scalars only (runtime-indexed arrays -> scratch, R6-R8 lesson).

#define GOLDEN   0x9E3779B9u
#define OUT_MASK ((1u << 22) - 1u)
#define NBIN  63
#define NPIV  8192
#define NKEY  16384

typedef float fx4 __attribute__((ext_vector_type(4)));
typedef int   ix4 __attribute__((ext_vector_type(4)));
typedef unsigned ux4 __attribute__((ext_vector_type(4)));

// bf16 ceil (round toward +inf), -0 canonicalized to +0.
__device__ __forceinline__ unsigned bf16c(float x) {
    const unsigned b = __float_as_uint(x);
    unsigned t = ((int)b >= 0) ? ((b + 0xFFFFu) >> 16) : (b >> 16);
    return (t == 0x8000u) ? 0u : t;
}

// ---------------- build (no atomics, no clear) ----------------
__global__ __launch_bounds__(256) void build_tables_kernel(
    const int* __restrict__ fids, const float* __restrict__ bins,
    float* __restrict__ qtab, ux4* __restrict__ spiv16_g,
    unsigned char* __restrict__ scal_g, int F)
{
    const int t = blockIdx.x * blockDim.x + threadIdx.x;
    if (t >= F * 64) return;
    const int r = t >> 6;
    const int j = t & 63;
    const unsigned uk = (unsigned)fids[r];
    const float* src = bins + (size_t)r * NBIN;

    if (uk < (unsigned)NPIV) {
        qtab[((size_t)uk << 6) + j] = (j < NBIN) ? src[j] : INFINITY;
        if (j == 0) {
            const unsigned p0 = bf16c(src[7]),  p1 = bf16c(src[15]),
                           p2 = bf16c(src[23]), p3 = bf16c(src[31]),
                           p4 = bf16c(src[39]), p5 = bf16c(src[47]),
                           p6 = bf16c(src[55]);
            const unsigned tag = 0x6000u | uk;        // uk < 8192
            ux4 q;
            q.x = p0 | (p1 << 16);
            q.y = p2 | (p3 << 16);
            q.z = p4 | (p5 << 16);
            q.w = p6 | (tag << 16);
            spiv16_g[uk] = q;
        }
    } else if (uk < (unsigned)NKEY && j == 0) {
        scal_g[uk - NPIV] = (unsigned char)(0x40u | (uk & 63u));
    }
}

// ---------------- generic fallback ----------------
__device__ __forceinline__ void hd_fallback(
    int k, float v, const int* __restrict__ fids, const float* __restrict__ bins,
    int F, int fsteps, float& okey, float& oval)
{
    int lo = 0, hi = F;
    for (int s = 0; s < fsteps; ++s) {
        int  mid  = (lo + hi) >> 1;
        int  mids = min(mid, F - 1);
        int  fv   = fids[mids];
        bool valid = lo < hi;
        bool right = valid && (fv < k);
        lo = right ? mid + 1 : lo;
        hi = (valid && !right) ? mid : hi;
    }
    const int  idx_safe   = min(lo, F - 1);
    const bool calibrated = (fids[idx_safe] == k);
    const float* brow = bins + (size_t)idx_safe * NBIN;
    int blo = 0, bhi = NBIN;
    #pragma unroll
    for (int s = 0; s < 6; ++s) {
        int   mid  = (blo + bhi) >> 1;
        int   mids = min(mid, NBIN - 1);
        float bv   = brow[mids];
        bool  valid = blo < bhi;
        bool  right = valid && (bv < v);
        blo = right ? mid + 1 : blo;
        bhi = (valid && !right) ? mid : bhi;
    }
    const uint32_t h = ((uint32_t)k * GOLDEN + (uint32_t)blo) * GOLDEN;
    okey = calibrated ? (float)(h & OUT_MASK) : (float)((uint32_t)k & OUT_MASK);
    oval = calibrated ? 1.0f : v;
}

__device__ __forceinline__ int hd_cmp8(fx4 a, fx4 b, float v) {
    return (a.x < v) + (a.y < v) + (a.z < v) + (a.w < v)
         + (b.x < v) + (b.y < v) + (b.z < v) + (b.w < v);
}

// fp32-exact bin from the 32B leaf window t of the qtab row (bf16 header
// may underestimate t: all-8-less means true window is higher -> bump).
__device__ __forceinline__ int hd_leaf_bin(const char* qb, unsigned u,
                                           float v, int t)
{
    for (;;) {
        const char* p = qb + ((u << 8) + (unsigned)(t << 5));
        const fx4 a = *reinterpret_cast<const fx4*>(p);
        const fx4 b = *reinterpret_cast<const fx4*>(p + 16);
        const int cnt = hd_cmp8(a, b, v);
        if (__builtin_expect(cnt == 8 && t < 7, 0)) { ++t; continue; }
        return (t << 3) + cnt;
    }
}

// ---------------- main ----------------
__global__ __launch_bounds__(1024, 4) void hd_main_kernel(
    const int* __restrict__ keys, const float* __restrict__ vals,
    const int* __restrict__ fids, const float* __restrict__ bins,
    const float* __restrict__ qtab, const ux4* __restrict__ spiv16_g,
    const unsigned char* __restrict__ scal_g,
    float* __restrict__ out_keys, float* __restrict__ out_vals,
    int n, int F, int fsteps, int nchunks)
{
    extern __shared__ char smem[];
    ux4*      spiv16 = reinterpret_cast<ux4*>(smem);             // 8192 x 16B
    unsigned* scal   = reinterpret_cast<unsigned*>(smem + (size_t)NPIV * 16);

    const int tid = threadIdx.x;
    for (int i = tid; i < NPIV; i += (int)blockDim.x) spiv16[i] = spiv16_g[i];
    const unsigned* scal_g32 = reinterpret_cast<const unsigned*>(scal_g);
    for (int i = tid; i < NPIV / 4; i += (int)blockDim.x) scal[i] = scal_g32[i];
    __syncthreads();

    const unsigned char* scal_b = reinterpret_cast<const unsigned char*>(scal);
    const char* qb = reinterpret_cast<const char*>(qtab);
    const int nthreads = (int)(gridDim.x * blockDim.x);

    for (int c = blockIdx.x * blockDim.x + tid; c < nchunks; c += nthreads) {
        const int i0 = c * 4;
        int   k0, k1, k2, k3;
        float v0, v1, v2, v3;
        const bool full = (i0 + 3 < n);
        if (full) {
            // R15 change: PLAIN cached loads (no nontemporal hint) so the
            // chain head rides L2/L3 (~200cy) instead of raw HBM (~900cy).
            const ix4 ka = *reinterpret_cast<const ix4*>(keys + i0);
            const fx4 va = *reinterpret_cast<const fx4*>(vals + i0);
            k0 = ka.x; k1 = ka.y; k2 = ka.z; k3 = ka.w;
            v0 = va.x; v1 = va.y; v2 = va.z; v3 = va.w;
        } else {
            k0 = keys[min(i0 + 0, n - 1)]; v0 = vals[min(i0 + 0, n - 1)];
            k1 = keys[min(i0 + 1, n - 1)]; v1 = vals[min(i0 + 1, n - 1)];
            k2 = keys[min(i0 + 2, n - 1)]; v2 = vals[min(i0 + 2, n - 1)];
            k3 = keys[min(i0 + 3, n - 1)]; v3 = vals[min(i0 + 3, n - 1)];
        }

        const unsigned u0 = (unsigned)k0, u1 = (unsigned)k1,
                       u2 = (unsigned)k2, u3 = (unsigned)k3;

        // ---- P1: 4 LDS headers (ds_read_b128), back-to-back ----
        const ux4 h0 = spiv16[u0 < (unsigned)NPIV ? u0 : 0u];
        const ux4 h1 = spiv16[u1 < (unsigned)NPIV ? u1 : 0u];
        const ux4 h2 = spiv16[u2 < (unsigned)NPIV ? u2 : 0u];
        const ux4 h3 = spiv16[u3 < (unsigned)NPIV ? u3 : 0u];

        // ---- P2: classify + 8-ary bf16 window (sound underestimate) ----
#define HD_BF(B) __uint_as_float((B) << 16)
#define HD_P2(J)                                                              \
        const bool cal##J = (u##J < (unsigned)NPIV) &&                        \
                            ((h##J.w >> 16) == (0x6000u | u##J));             \
        const int t##J = (HD_BF(h##J.x & 0xFFFFu) < v##J)                     \
                       + (HD_BF(h##J.x >> 16)     < v##J)                     \
                       + (HD_BF(h##J.y & 0xFFFFu) < v##J)                     \
                       + (HD_BF(h##J.y >> 16)     < v##J)                     \
                       + (HD_BF(h##J.z & 0xFFFFu) < v##J)                     \
                       + (HD_BF(h##J.z >> 16)     < v##J)                     \
                       + (HD_BF(h##J.w & 0xFFFFu) < v##J);                    \
        const unsigned hs##J = u##J - (unsigned)NPIV;                         \
        const bool rare##J =                                                  \
            (u##J >= (unsigned)NKEY) ||                                       \
            ((hs##J < (unsigned)NPIV) &&                                      \
             (scal_b[hs##J < (unsigned)NPIV ? hs##J : 0u] ==                  \
              (unsigned char)(0x40u | (u##J & 63u))));
        HD_P2(0) HD_P2(1) HD_P2(2) HD_P2(3)
#undef HD_P2
#undef HD_BF

        // ---- P3: 32B leaf gather + hash (calibrated lanes only) ----
        float ok0, ok1, ok2, ok3, ov0, ov1, ov2, ov3;
#define HD_P3(J)                                                              \
        if (cal##J) {                                                         \
            const int bin = hd_leaf_bin(qb, u##J, v##J, t##J);                \
            const uint32_t h = (u##J * GOLDEN + (uint32_t)bin) * GOLDEN;      \
            ok##J = (float)(h & OUT_MASK);                                    \
            ov##J = 1.0f;                                                     \
        } else {                                                              \
            ok##J = (float)(u##J & OUT_MASK);                                 \
            ov##J = v##J;                                                     \
        }
        HD_P3(0) HD_P3(1) HD_P3(2) HD_P3(3)
#undef HD_P3

        // ---- cold path (absent in bench data) ----
        if (__builtin_expect(rare0 | rare1 | rare2 | rare3, 0)) {
            if (rare0) hd_fallback(k0, v0, fids, bins, F, fsteps, ok0, ov0);
            if (rare1) hd_fallback(k1, v1, fids, bins, F, fsteps, ok1, ov1);
            if (rare2) hd_fallback(k2, v2, fids, bins, F, fsteps, ok2, ov2);
            if (rare3) hd_fallback(k3, v3, fids, bins, F, fsteps, ok3, ov3);
        }

        if (full) {
            fx4 s;
            s.x = ok0; s.y = ok1; s.z = ok2; s.w = ok3;
            __builtin_nontemporal_store(s, reinterpret_cast<fx4*>(out_keys + i0));
            s.x = ov0; s.y = ov1; s.z = ov2; s.w = ov3;
            __builtin_nontemporal_store(s, reinterpret_cast<fx4*>(out_vals + i0));
        } else {
            if (i0 + 0 < n) { out_keys[i0 + 0] = ok0; out_vals[i0 + 0] = ov0; }
            if (i0 + 1 < n) { out_keys[i0 + 1] = ok1; out_vals[i0 + 1] = ov1; }
            if (i0 + 2 < n) { out_keys[i0 + 2] = ok2; out_vals[i0 + 2] = ov2; }
            if (i0 + 3 < n) { out_keys[i0 + 3] = ok3; out_vals[i0 + 3] = ov3; }
        }
    }
}

// Pure binary-search kernel: used only if LDS or workspace is insufficient.
__global__ __launch_bounds__(256) void hd_simple_kernel(
    const int* __restrict__ keys, const float* __restrict__ vals,
    const int* __restrict__ fids, const float* __restrict__ bins,
    float* __restrict__ out_keys, float* __restrict__ out_vals,
    int n, int F, int fsteps)
{
    const int gid = blockIdx.x * blockDim.x + threadIdx.x;
    const int i0 = gid * 4;
    if (i0 >= n) return;
    #pragma unroll
    for (int j = 0; j < 4; ++j) {
        int idx = min(i0 + j, n - 1);
        float okey, oval;
        hd_fallback(keys[idx], vals[idx], fids, bins, F, fsteps, okey, oval);
        if (i0 + j < n) { out_keys[i0 + j] = okey; out_vals[i0 + j] = oval; }
    }
}

extern "C" void kernel_launch(void* const* d_in, const int* in_sizes, int n_in,
                              void* d_out, int out_size, void* d_ws, size_t ws_size,
                              hipStream_t stream) {
    const int*   keys = (const int*)d_in[0];
    const float* vals = (const float*)d_in[1];
    const int*   fids = (const int*)d_in[2];
    const float* bins = (const float*)d_in[3];

    const int n = in_sizes[0];
    const int F = in_sizes[2];

    int fsteps = 0;
    while ((1 << fsteps) < F + 1) ++fsteps;

    float* out_keys = (float*)d_out;
    float* out_vals = (float*)d_out + n;

    // ws: qtab (2 MB) | spiv16 (128 KB) | scal (8 KB)
    const size_t qtab_bytes = (size_t)NPIV * 64 * sizeof(float);
    const size_t spiv_bytes = (size_t)NPIV * 16;
    const size_t scal_bytes = (size_t)NPIV;
    const size_t ws_need    = qtab_bytes + spiv_bytes + scal_bytes;
    const size_t lds_bytes  = spiv_bytes + scal_bytes;   // 139264 B

    int max_lds = 0;
    hipDeviceGetAttribute(&max_lds, hipDeviceAttributeMaxSharedMemoryPerBlock, 0);

    const bool fast = (ws_size >= ws_need) && ((size_t)max_lds >= lds_bytes) &&
                      (in_sizes[3] == F * NBIN) && (F <= NPIV);

    if (fast) {
        float*         qtab     = (float*)d_ws;
        ux4*           spiv16_g = (ux4*)((char*)d_ws + qtab_bytes);
        unsigned char* scal_g   = (unsigned char*)d_ws + qtab_bytes + spiv_bytes;

        build_tables_kernel<<<(F * 64 + 255) / 256, 256, 0, stream>>>(
            fids, bins, qtab, spiv16_g, scal_g, F);

        (void)hipFuncSetAttribute(
            reinterpret_cast<const void*>(hd_main_kernel),
            hipFuncAttributeMaxDynamicSharedMemorySize, (int)lds_bytes);

        const int threads = 1024;
        const int nblocks = 256;           // 1 block/CU; LDS fill once per CU
        const int nchunks = (n + 3) / 4;
        hd_main_kernel<<<nblocks, threads, lds_bytes, stream>>>(
            keys, vals, fids, bins, qtab, spiv16_g, scal_g,
            out_keys, out_vals, n, F, fsteps, nchunks);
    } else {
        const int threads = 256;
        const int grid = (n + threads * 4 - 1) / (threads * 4);
        hd_simple_kernel<<<grid, threads, 0, stream>>>(
            keys, vals, fids, bins, out_keys, out_vals, n, F, fsteps);
    }
}